// Round 13
// baseline (13858.167 us; speedup 1.0000x reference)
//
#include <hip/hip_runtime.h>
#include <cstdint>

#define NB 128   // batch
#define NS 1024  // seq len
#define NV 128   // input dim
#define NH 256   // hidden
#define CH 64    // chunk length
#define NCH (NS / CH)

typedef _Float16 f16;
typedef _Float16 h2 __attribute__((ext_vector_type(2)));
typedef uint32_t u32;

static __device__ __forceinline__ float fdot2(u32 a, u32 b, float c) {
  return __builtin_amdgcn_fdot2(__builtin_bit_cast(h2, a),
                                __builtin_bit_cast(h2, b), c, false);
}
static __device__ __forceinline__ u32 pkh(float a, float b) {  // RTN
  union { h2 h; u32 u; } cv; cv.h = h2{(f16)a, (f16)b}; return cv.u;
}
static __device__ __forceinline__ u32 pkz(float a, float b) {  // RTZ (x only)
  return __builtin_bit_cast(u32, __builtin_amdgcn_cvt_pkrtz(a, b));
}
static __device__ __forceinline__ float sigm(float x) { return 1.f / (1.f + __expf(-x)); }
static __device__ __forceinline__ float tanh_(float x) { return 1.f - 2.f / (__expf(2.f * x) + 1.f); }

// Pin into ARCH VGPRs (opaque def, no remat).
static __device__ __forceinline__ void pin4v(uint4& v) {
  asm volatile("" : "+v"(v.x), "+v"(v.y), "+v"(v.z), "+v"(v.w));
}
// Pin into ACCUM VGPRs (AGPRs): the unused half of the gfx950 unified file.
// Demand exceeds the 128 arch-VGPRs the allocator grants (r4-r12 evidence);
// "+a" makes overflow AGPR-resident: access = v_accvgpr_read (~2cyc VALU)
// instead of per-step scratch/L2 reload.
static __device__ __forceinline__ void pin4a(uint4& v) {
  asm volatile("" : "+a"(v.x), "+a"(v.y), "+a"(v.z), "+a"(v.w));
}

// ---------------------------------------------------------------------------
// prepack: all four weight matrices f32 -> packed f16 pairs, once per call.
// ---------------------------------------------------------------------------
__global__ __launch_bounds__(1024) void prepack_kernel(
    const float* __restrict__ Wih0, const float* __restrict__ Wih1,
    const float* __restrict__ Whh0, const float* __restrict__ Whh1,
    u32* __restrict__ Wih0p, u32* __restrict__ Wih1p,
    u32* __restrict__ Whh0p, u32* __restrict__ Whh1p) {
  const int g = blockIdx.x * 1024 + threadIdx.x;
  const float* src; u32* dst; int off;
  if (g < 65536)       { src = Wih0; dst = Wih0p; off = g; }
  else if (g < 196608) { src = Wih1; dst = Wih1p; off = g - 65536; }
  else if (g < 327680) { src = Whh0; dst = Whh0p; off = g - 196608; }
  else                 { src = Whh1; dst = Whh1p; off = g - 327680; }
  dst[off] = pkh(src[2 * off], src[2 * off + 1]);
}

// ---------------------------------------------------------------------------
// gemm pair. Per-row fragment split: 11 pinned-v + 13 pinned-a + 8 LDS
// (gemm1); gemm0: 8 v + 8 a per row. Input panel staged to LDS (r12).
// ---------------------------------------------------------------------------
__global__ __attribute__((amdgpu_flat_work_group_size(512, 512),
                          amdgpu_waves_per_eu(2, 2)))
void gemm_pair_kernel(
    const u32* __restrict__ g1_in, const u32* __restrict__ g1_Wp,
    const float* __restrict__ g1_bih, const float* __restrict__ g1_bhh,
    f16* __restrict__ g1_xg, int g1_t0, int g1_on,
    const float* __restrict__ g0_x, const u32* __restrict__ g0_Wp,
    const float* __restrict__ g0_bih, const float* __restrict__ g0_bhh,
    f16* __restrict__ g0_xg, int g0_t0, int g0_on) {
  __shared__ uint4 wL0[8][512];
  __shared__ uint4 wL1[8][512];
  __shared__ __align__(16) u32 panel[32 * 128];  // 16 KiB input panel
  const int blk = blockIdx.x;
  const int tid = threadIdx.x;
  const int r0 = tid, r1 = tid + 512;

  if (blk < 256) {
    if (!g1_on) return;
    const int b = blk >> 1, tpart = blk & 1;
    const uint4* src = (const uint4*)(g1_in + ((size_t)b * NS + g1_t0 + tpart * 32) * 128);
    ((uint4*)panel)[tid] = src[tid];
    ((uint4*)panel)[tid + 512] = src[tid + 512];
    uint4 w0v[11], w0a[13], w1v[11], w1a[13];
    {
      const u32* p0 = g1_Wp + (size_t)r0 * 128;
      const u32* p1 = g1_Wp + (size_t)r1 * 128;
#pragma unroll
      for (int k = 0; k < 32; ++k) {
        uint4 v0 = *(const uint4*)(p0 + 4 * k);
        uint4 v1 = *(const uint4*)(p1 + 4 * k);
        if (k < 11) { w0v[k] = v0; w1v[k] = v1; }
        else if (k < 24) { w0a[k - 11] = v0; w1a[k - 11] = v1; }
        else { wL0[k - 24][tid] = v0; wL1[k - 24][tid] = v1; }
      }
    }
#pragma unroll
    for (int k = 0; k < 11; ++k) { pin4v(w0v[k]); pin4v(w1v[k]); }
#pragma unroll
    for (int k = 0; k < 13; ++k) { pin4a(w0a[k]); pin4a(w1a[k]); }
    const float bs0 = g1_bih[r0] + g1_bhh[r0];
    const float bs1 = g1_bih[r1] + g1_bhh[r1];
    __syncthreads();
#pragma unroll 1
    for (int tl = 0; tl < 32; ++tl) {
      float a0 = 0.f, a1 = 0.f;
#pragma unroll
      for (int k = 0; k < 32; ++k) {
        uint4 xv = *(const uint4*)&panel[tl * 128 + 4 * k];  // uniform broadcast
        uint4 wa = (k < 11) ? w0v[k] : (k < 24) ? w0a[k - 11] : wL0[k - 24][tid];
        uint4 wb = (k < 11) ? w1v[k] : (k < 24) ? w1a[k - 11] : wL1[k - 24][tid];
        a0 = fdot2(wa.x, xv.x, a0); a0 = fdot2(wa.y, xv.y, a0);
        a0 = fdot2(wa.z, xv.z, a0); a0 = fdot2(wa.w, xv.w, a0);
        a1 = fdot2(wb.x, xv.x, a1); a1 = fdot2(wb.y, xv.y, a1);
        a1 = fdot2(wb.z, xv.z, a1); a1 = fdot2(wb.w, xv.w, a1);
      }
      f16* op = g1_xg + ((size_t)b * CH + tpart * 32 + tl) * 1024;
      op[r0] = (f16)(a0 + bs0);
      op[r1] = (f16)(a1 + bs1);
    }
  } else {
    if (!g0_on) return;
    const int idx = blk - 256;
    const int b = idx >> 1, tpart = idx & 1;
    {
      const float4* src = (const float4*)(g0_x + ((size_t)b * NS + g0_t0 + tpart * 32) * NV);
      float4 a = src[2 * tid];
      float4 c = src[2 * tid + 1];
      ((uint4*)panel)[tid] = uint4{pkz(a.x, a.y), pkz(a.z, a.w), pkz(c.x, c.y), pkz(c.z, c.w)};
    }
    uint4 w0v[8], w0a[8], w1v[8], w1a[8];
    {
      const u32* p0 = g0_Wp + (size_t)r0 * 64;
      const u32* p1 = g0_Wp + (size_t)r1 * 64;
#pragma unroll
      for (int k = 0; k < 16; ++k) {
        uint4 v0 = *(const uint4*)(p0 + 4 * k);
        uint4 v1 = *(const uint4*)(p1 + 4 * k);
        if (k < 8) { w0v[k] = v0; w1v[k] = v1; }
        else { w0a[k - 8] = v0; w1a[k - 8] = v1; }
      }
    }
#pragma unroll
    for (int k = 0; k < 8; ++k) {
      pin4v(w0v[k]); pin4v(w1v[k]); pin4a(w0a[k]); pin4a(w1a[k]);
    }
    const float bs0 = g0_bih[r0] + g0_bhh[r0];
    const float bs1 = g0_bih[r1] + g0_bhh[r1];
    __syncthreads();
#pragma unroll 1
    for (int tl = 0; tl < 32; ++tl) {
      float a0 = 0.f, a1 = 0.f;
#pragma unroll
      for (int k = 0; k < 16; ++k) {
        uint4 xv = *(const uint4*)&panel[tl * 64 + 4 * k];  // uniform broadcast
        uint4 wa = (k < 8) ? w0v[k] : w0a[k - 8];
        uint4 wb = (k < 8) ? w1v[k] : w1a[k - 8];
        a0 = fdot2(wa.x, xv.x, a0); a0 = fdot2(wa.y, xv.y, a0);
        a0 = fdot2(wa.z, xv.z, a0); a0 = fdot2(wa.w, xv.w, a0);
        a1 = fdot2(wb.x, xv.x, a1); a1 = fdot2(wb.y, xv.y, a1);
        a1 = fdot2(wb.z, xv.z, a1); a1 = fdot2(wb.w, xv.w, a1);
      }
      f16* op = g0_xg + ((size_t)b * CH + tpart * 32 + tl) * 1024;
      op[r0] = (f16)(a0 + bs0);
      op[r1] = (f16)(a1 + bs1);
    }
  }
}

// ---------------------------------------------------------------------------
// scan pair. Per-row fragment split: 11 pinned-v + 13 pinned-a + 8 LDS.
// Totals/thread: 22 v-frags (88 u32, fits the 128 granted), 26 a-frags
// (104 AGPRs; 2 waves x (128+104) = 464 <= 512 unified pool), 16 LDS frags.
// h(t-1) via uniform ds_read_b128 broadcast; one barrier/step (r11 body).
// ---------------------------------------------------------------------------
__global__ __attribute__((amdgpu_flat_work_group_size(512, 512),
                          amdgpu_waves_per_eu(2, 2)))
void scan_pair_kernel(
    const f16* __restrict__ xgA, const u32* __restrict__ WhhAp,
    u32* __restrict__ slotsA, u32* __restrict__ hseedA, float* __restrict__ carryA,
    int t0A, int firstA, int onA,
    const f16* __restrict__ xgB, const u32* __restrict__ WhhBp,
    u32* __restrict__ slotsB, u32* __restrict__ hseedB, float* __restrict__ carryB,
    int t0B, int firstB, int onB) {
  __shared__ uint4 wL0[8][512];                 // r0-row overflow, tid-indexed
  __shared__ uint4 wL1[8][512];                 // r1-row overflow, tid-indexed
  __shared__ __align__(16) u32 hbuf[2][128];    // h as 256 f16, double-buffered

  const int blk = blockIdx.x;
  const int tid = threadIdx.x;
  const f16* xg; const u32* Whhp; u32* slots; u32* hseed; float* carry;
  int t0, first, b;
  if (blk < 128) {
    if (!onA) return;
    b = blk; xg = xgA; Whhp = WhhAp; slots = slotsA; hseed = hseedA; carry = carryA;
    t0 = t0A; first = firstA;
  } else {
    if (!onB) return;
    b = blk - 128; xg = xgB; Whhp = WhhBp; slots = slotsB; hseed = hseedB; carry = carryB;
    t0 = t0B; first = firstB;
  }
  const int p = tid & 1;
  const int u = tid >> 1;
  const int r0 = p * 256 + u;   // gate i (p=0) / f (p=1)
  const int r1 = r0 + 512;      // gate g (p=0) / o (p=1)

  uint4 w0v[11], w0a[13], w1v[11], w1a[13];
  {
    const u32* p0 = Whhp + (size_t)r0 * 128;
    const u32* p1 = Whhp + (size_t)r1 * 128;
#pragma unroll
    for (int k = 0; k < 32; ++k) {
      uint4 v0 = *(const uint4*)(p0 + 4 * k);
      uint4 v1 = *(const uint4*)(p1 + 4 * k);
      if (k < 11) { w0v[k] = v0; w1v[k] = v1; }
      else if (k < 24) { w0a[k - 11] = v0; w1a[k - 11] = v1; }
      else { wL0[k - 24][tid] = v0; wL1[k - 24][tid] = v1; }
    }
  }
#pragma unroll
  for (int k = 0; k < 11; ++k) { pin4v(w0v[k]); pin4v(w1v[k]); }
#pragma unroll
  for (int k = 0; k < 13; ++k) { pin4a(w0a[k]); pin4a(w1a[k]); }
  float c;
  if (first) {
    if (tid < 128) hbuf[0][tid] = 0u;
    c = 0.f;
  } else {
    if (tid < 128) hbuf[0][tid] = hseed[b * 128 + tid];
    c = carry[b * 256 + u];
  }
  __syncthreads();

#pragma unroll 1
  for (int tl = 0; tl < CH; ++tl) {
    const int cur = tl & 1, nxt = cur ^ 1;
    const f16* xp = xg + ((size_t)b * CH + tl) * 1024;
    const float xa = (float)xp[r0];
    const float xb = (float)xp[r1];

    float a0 = 0.f, a1 = 0.f;
#pragma unroll
    for (int k = 0; k < 32; ++k) {
      uint4 hk = *(const uint4*)&hbuf[cur][4 * k];  // uniform addr -> broadcast
      const uint4 wa = (k < 11) ? w0v[k] : (k < 24) ? w0a[k - 11] : wL0[k - 24][tid];
      const uint4 wb = (k < 11) ? w1v[k] : (k < 24) ? w1a[k - 11] : wL1[k - 24][tid];
      a0 = fdot2(wa.x, hk.x, a0); a0 = fdot2(wa.y, hk.y, a0);
      a0 = fdot2(wa.z, hk.z, a0); a0 = fdot2(wa.w, hk.w, a0);
      a1 = fdot2(wb.x, hk.x, a1); a1 = fdot2(wb.y, hk.y, a1);
      a1 = fdot2(wb.z, hk.z, a1); a1 = fdot2(wb.w, hk.w, a1);
    }
    a0 += xa; a1 += xb;
    const float px0 = __shfl_xor(a0, 1);   // partner lane: other two gates
    const float px1 = __shfl_xor(a1, 1);
    const float ai = p ? px0 : a0;
    const float ag = p ? px1 : a1;
    const float af = p ? a0 : px0;
    const float ao = p ? a1 : px1;
    const float gi = sigm(ai), gg = tanh_(ag), gf = sigm(af), go = sigm(ao);
    c = gf * c + gi * gg;                  // redundant in both lanes (same value)
    const float h = go * tanh_(c);
    if (p == 0) {
      ((f16*)hbuf[nxt])[u] = (f16)h;
      ((f16*)(slots + ((size_t)b * NS + t0 + tl) * 128))[u] = (f16)h;
    }
    __syncthreads();  // single barrier: h(t) visible for next step
  }
  if (tid < 128) hseed[b * 128 + tid] = hbuf[0][tid];  // CH even -> final in [0]
  if (p == 0) carry[b * 256 + u] = c;
}

// ---------------------------------------------------------------------------
// outproj: out = Wout·h1 + b, IN PLACE over d_out slots. r11/r12 version.
// ---------------------------------------------------------------------------
#define OPS 140
static __device__ __forceinline__ int swzc(int col) { return col + 4 * (col >> 5); }

__global__ __launch_bounds__(1024) void outproj_kernel(
    const float* __restrict__ Wout, const float* __restrict__ bout,
    u32* __restrict__ io) {
  const int bs = blockIdx.x;  // 2048 blocks
  const int b = bs >> 4;
  const int t0 = (bs & 15) * 64;
  const int tid = threadIdx.x;
  const int p = tid & 7;
  const int vq = tid >> 3;

  __shared__ u32 h1L[64 * OPS];
  __shared__ float outL[64 * OPS];

  const u32* src = io + ((size_t)b * NS + t0) * 128;
  uint4 s0 = *(const uint4*)(src + (size_t)tid * 8);
  uint4 s1 = *(const uint4*)(src + (size_t)tid * 8 + 4);

  u32 wo[16];
  const float* pw = Wout + (size_t)vq * NH + p * 32;
#pragma unroll
  for (int k = 0; k < 8; ++k) {
    float4 w4 = *(const float4*)(pw + 4 * k);
    wo[2 * k] = pkh(w4.x, w4.y); wo[2 * k + 1] = pkh(w4.z, w4.w);
  }
  const float bo = bout[vq];

  {
    const int sr = tid >> 4;
    const int sc = (tid & 15) * 8;
    const int base = sr * OPS + swzc(sc);
    *(uint4*)&h1L[base] = s0;
    *(uint4*)&h1L[base + 4] = s1;
  }
  __syncthreads();

#pragma unroll 4
  for (int s = 0; s < 64; ++s) {
    float oa = 0.f;
#pragma unroll
    for (int q = 0; q < 4; ++q) {
      uint4 hq = *(const uint4*)&h1L[s * OPS + swzc(p * 16 + 4 * q)];
      u32 hw[4] = {hq.x, hq.y, hq.z, hq.w};
#pragma unroll
      for (int j = 0; j < 4; ++j) oa = fdot2(wo[4 * q + j], hw[j], oa);
    }
    oa += __shfl_xor(oa, 1);
    oa += __shfl_xor(oa, 2);
    oa += __shfl_xor(oa, 4);
    if (p == 0) outL[s * OPS + swzc(vq)] = oa + bo;
  }
  __syncthreads();

  float* df = (float*)(io + ((size_t)b * NS + t0) * 128);
  {
    const int sr = tid >> 4;
    const int sc = (tid & 15) * 8;
    const int base = sr * OPS + swzc(sc);
    *(float4*)(df + (size_t)tid * 8) = *(float4*)&outL[base];
    *(float4*)(df + (size_t)tid * 8 + 4) = *(float4*)&outL[base + 4];
  }
}

extern "C" void kernel_launch(void* const* d_in, const int* in_sizes, int n_in,
                              void* d_out, int out_size, void* d_ws, size_t ws_size,
                              hipStream_t stream) {
  const float* x    = (const float*)d_in[0];
  const float* Wih0 = (const float*)d_in[1];
  const float* Whh0 = (const float*)d_in[2];
  const float* bih0 = (const float*)d_in[3];
  const float* bhh0 = (const float*)d_in[4];
  const float* Wih1 = (const float*)d_in[5];
  const float* Whh1 = (const float*)d_in[6];
  const float* bih1 = (const float*)d_in[7];
  const float* bhh1 = (const float*)d_in[8];
  const float* Wout = (const float*)d_in[9];
  const float* bout = (const float*)d_in[10];

  // ws (< 38 MiB): xg0 | xg1 | hseed/carry | packed weights
  f16* xg0 = (f16*)d_ws;
  f16* xg1 = (f16*)((char*)d_ws + (16u << 20));
  u32* hseed0 = (u32*)((char*)d_ws + (32u << 20));
  u32* hseed1 = (u32*)((char*)d_ws + (32u << 20) + (64u << 10));
  float* carry0 = (float*)((char*)d_ws + (32u << 20) + (128u << 10));
  float* carry1 = (float*)((char*)d_ws + (32u << 20) + (256u << 10));
  u32* Wih0p = (u32*)((char*)d_ws + (34u << 20));
  u32* Wih1p = (u32*)((char*)d_ws + (35u << 20));
  u32* Whh0p = (u32*)((char*)d_ws + (36u << 20));
  u32* Whh1p = (u32*)((char*)d_ws + (37u << 20));
  u32* slots = (u32*)d_out;  // h0 -> h1 -> f32 out, in place per chunk row

  prepack_kernel<<<448, 1024, 0, stream>>>(Wih0, Wih1, Whh0, Whh1,
                                           Wih0p, Wih1p, Whh0p, Whh1p);

  // prologue: gemm0(0); scan0(0)
  gemm_pair_kernel<<<512, 512, 0, stream>>>(
      nullptr, nullptr, nullptr, nullptr, nullptr, 0, 0,
      x, Wih0p, bih0, bhh0, xg0, 0, 1);
  scan_pair_kernel<<<256, 512, 0, stream>>>(
      nullptr, nullptr, nullptr, nullptr, nullptr, 0, 0, 0,
      xg0, Whh0p, slots, hseed0, carry0, 0, 1, 1);

  // pipeline: {gemm1(s) || gemm0(s+1)}; then {scan1(s) || scan0(s+1)}
  for (int s = 0; s < NCH; ++s) {
    const int g0on = (s + 1 < NCH);
    gemm_pair_kernel<<<512, 512, 0, stream>>>(
        slots, Wih1p, bih1, bhh1, xg1, s * CH, 1,
        x, Wih0p, bih0, bhh0, xg0, (s + 1) * CH, g0on);
    scan_pair_kernel<<<256, 512, 0, stream>>>(
        xg1, Whh1p, slots, hseed1, carry1, s * CH, (s == 0) ? 1 : 0, 1,
        xg0, Whh0p, slots, hseed0, carry0, (s + 1) * CH, 0, g0on);
  }
  outproj_kernel<<<2048, 1024, 0, stream>>>(Wout, bout, slots);
}

// Round 14
// 5977.449 us; speedup vs baseline: 2.3184x; 2.3184x over previous
//
#include <hip/hip_runtime.h>
#include <cstdint>

#define NB 128   // batch
#define NS 1024  // seq len
#define NV 128   // input dim
#define NH 256   // hidden
#define CH 64    // chunk length
#define NCH (NS / CH)

typedef _Float16 f16;
typedef _Float16 h2 __attribute__((ext_vector_type(2)));
typedef uint32_t u32;

static __device__ __forceinline__ float fdot2(u32 a, u32 b, float c) {
  return __builtin_amdgcn_fdot2(__builtin_bit_cast(h2, a),
                                __builtin_bit_cast(h2, b), c, false);
}
static __device__ __forceinline__ u32 pkh(float a, float b) {  // RTN
  union { h2 h; u32 u; } cv; cv.h = h2{(f16)a, (f16)b}; return cv.u;
}
static __device__ __forceinline__ u32 pkz(float a, float b) {  // RTZ (x only)
  return __builtin_bit_cast(u32, __builtin_amdgcn_cvt_pkrtz(a, b));
}
static __device__ __forceinline__ float sigm(float x) { return 1.f / (1.f + __expf(-x)); }
static __device__ __forceinline__ float tanh_(float x) { return 1.f - 2.f / (__expf(2.f * x) + 1.f); }

// Opaque asm def: allocator cannot rematerialize (no AGPR constraint — r13
// showed "+a" forces copy-storms; with 1024-thread WGs demand fits arch VGPRs).
static __device__ __forceinline__ void pin4v(uint4& v) {
  asm volatile("" : "+v"(v.x), "+v"(v.y), "+v"(v.z), "+v"(v.w));
}

// ---------------------------------------------------------------------------
// prepack: four weight matrices f32 -> packed f16 pairs, once per call.
// ---------------------------------------------------------------------------
__global__ __launch_bounds__(1024) void prepack_kernel(
    const float* __restrict__ Wih0, const float* __restrict__ Wih1,
    const float* __restrict__ Whh0, const float* __restrict__ Whh1,
    u32* __restrict__ Wih0p, u32* __restrict__ Wih1p,
    u32* __restrict__ Whh0p, u32* __restrict__ Whh1p) {
  const int g = blockIdx.x * 1024 + threadIdx.x;
  const float* src; u32* dst; int off;
  if (g < 65536)       { src = Wih0; dst = Wih0p; off = g; }
  else if (g < 196608) { src = Wih1; dst = Wih1p; off = g - 65536; }
  else if (g < 327680) { src = Whh0; dst = Whh0p; off = g - 196608; }
  else                 { src = Whh1; dst = Whh1p; off = g - 327680; }
  dst[off] = pkh(src[2 * off], src[2 * off + 1]);
}

// ---------------------------------------------------------------------------
// gemm pair, 1024 threads: ONE row per thread -> weight demand 128/64 u32,
// fits the 128-VGPR class with no AGPR copy traffic (r12's 512-thr version
// demanded 256 u32/thread -> ~100 silent AGPRs + accvgpr_read per use).
//  blocks [0,256):  gemm1(s): row=tid; 24 uint4 pinned-v + 8 LDS.
//  blocks [256,512): gemm0(s+1): row=tid; 16 uint4 all pinned-v.
// Input panel (32 timesteps) staged in LDS, read uniform-broadcast.
// ---------------------------------------------------------------------------
__global__ __attribute__((amdgpu_flat_work_group_size(1024, 1024),
                          amdgpu_waves_per_eu(4, 4)))
void gemm_pair_kernel(
    const u32* __restrict__ g1_in, const u32* __restrict__ g1_Wp,
    const float* __restrict__ g1_bih, const float* __restrict__ g1_bhh,
    f16* __restrict__ g1_xg, int g1_t0, int g1_on,
    const float* __restrict__ g0_x, const u32* __restrict__ g0_Wp,
    const float* __restrict__ g0_bih, const float* __restrict__ g0_bhh,
    f16* __restrict__ g0_xg, int g0_t0, int g0_on) {
  __shared__ uint4 wL[8][1024];                  // 128 KiB weight overflow (g1)
  __shared__ __align__(16) u32 panel[32 * 128];  // 16 KiB input panel
  const int blk = blockIdx.x;
  const int tid = threadIdx.x;
  const int r = tid;

  if (blk < 256) {
    if (!g1_on) return;
    const int b = blk >> 1, tpart = blk & 1;
    // stage 32 timesteps of h0 (16 KiB) -> LDS, coalesced
    const uint4* src = (const uint4*)(g1_in + ((size_t)b * NS + g1_t0 + tpart * 32) * 128);
    ((uint4*)panel)[tid] = src[tid];
    uint4 w[24];
    {
      const u32* p0 = g1_Wp + (size_t)r * 128;
#pragma unroll
      for (int k = 0; k < 32; ++k) {
        uint4 v = *(const uint4*)(p0 + 4 * k);
        if (k < 24) w[k] = v;
        else wL[k - 24][tid] = v;
      }
    }
#pragma unroll
    for (int k = 0; k < 24; ++k) pin4v(w[k]);
    const float bs = g1_bih[r] + g1_bhh[r];
    __syncthreads();
#pragma unroll 1
    for (int tl = 0; tl < 32; ++tl) {
      float a = 0.f;
#pragma unroll
      for (int k = 0; k < 32; ++k) {
        uint4 xv = *(const uint4*)&panel[tl * 128 + 4 * k];  // uniform broadcast
        uint4 wa = (k < 24) ? w[k] : wL[k - 24][tid];
        a = fdot2(wa.x, xv.x, a); a = fdot2(wa.y, xv.y, a);
        a = fdot2(wa.z, xv.z, a); a = fdot2(wa.w, xv.w, a);
      }
      g1_xg[((size_t)b * CH + tpart * 32 + tl) * 1024 + r] = (f16)(a + bs);
    }
  } else {
    if (!g0_on) return;
    const int idx = blk - 256;
    const int b = idx >> 1, tpart = idx & 1;
    // stage 32 timesteps of x packed f32->f16 (8 KiB, threads < 512)
    if (tid < 512) {
      const float4* src = (const float4*)(g0_x + ((size_t)b * NS + g0_t0 + tpart * 32) * NV);
      float4 a = src[2 * tid];
      float4 c = src[2 * tid + 1];
      ((uint4*)panel)[tid] = uint4{pkz(a.x, a.y), pkz(a.z, a.w), pkz(c.x, c.y), pkz(c.z, c.w)};
    }
    uint4 w[16];
    {
      const u32* p0 = g0_Wp + (size_t)r * 64;
#pragma unroll
      for (int k = 0; k < 16; ++k) w[k] = *(const uint4*)(p0 + 4 * k);
    }
#pragma unroll
    for (int k = 0; k < 16; ++k) pin4v(w[k]);
    const float bs = g0_bih[r] + g0_bhh[r];
    __syncthreads();
#pragma unroll 1
    for (int tl = 0; tl < 32; ++tl) {
      float a = 0.f;
#pragma unroll
      for (int k = 0; k < 16; ++k) {
        uint4 xv = *(const uint4*)&panel[tl * 64 + 4 * k];  // uniform broadcast
        a = fdot2(w[k].x, xv.x, a); a = fdot2(w[k].y, xv.y, a);
        a = fdot2(w[k].z, xv.z, a); a = fdot2(w[k].w, xv.w, a);
      }
      g0_xg[((size_t)b * CH + tpart * 32 + tl) * 1024 + r] = (f16)(a + bs);
    }
  }
}

// ---------------------------------------------------------------------------
// scan pair, 1024 threads: thread (kh=tid&1, gp=(tid>>1)&1, u=tid>>2) owns the
// kh-half (128 cols) of rows r0=gp*256+u (i/f) and r1=r0+512 (g/o).
// Weights: 2 rows x 16 uint4 = 32 -> 24 pinned-v (96 u32) + 8 LDS (128 KiB).
// Demand ~115 u32 <= the 128-VGPR grant -> NO silent AGPR copies (the r12
// scan's 3x VALU inflation). 16 waves = 4/SIMD for latency hiding.
// Reduce: shfl_xor(1) sums kh-halves; shfl_xor(2) exchanges gate partners
// (r4-proven quad mapping). One barrier per step.
//  blocks [0,128) = scan1 chunk s; [128,256) = scan0 chunk s+1. 1 WG/CU.
// ---------------------------------------------------------------------------
__global__ __attribute__((amdgpu_flat_work_group_size(1024, 1024),
                          amdgpu_waves_per_eu(4, 4)))
void scan_pair_kernel(
    const f16* __restrict__ xgA, const u32* __restrict__ WhhAp,
    u32* __restrict__ slotsA, u32* __restrict__ hseedA, float* __restrict__ carryA,
    int t0A, int firstA, int onA,
    const f16* __restrict__ xgB, const u32* __restrict__ WhhBp,
    u32* __restrict__ slotsB, u32* __restrict__ hseedB, float* __restrict__ carryB,
    int t0B, int firstB, int onB) {
  __shared__ uint4 wL0[4][1024];                // r0-half overflow (64 KiB)
  __shared__ uint4 wL1[4][1024];                // r1-half overflow (64 KiB)
  __shared__ __align__(16) u32 hbuf[2][128];    // h as 256 f16, double-buffered

  const int blk = blockIdx.x;
  const int tid = threadIdx.x;
  const f16* xg; const u32* Whhp; u32* slots; u32* hseed; float* carry;
  int t0, first, b;
  if (blk < 128) {
    if (!onA) return;
    b = blk; xg = xgA; Whhp = WhhAp; slots = slotsA; hseed = hseedA; carry = carryA;
    t0 = t0A; first = firstA;
  } else {
    if (!onB) return;
    b = blk - 128; xg = xgB; Whhp = WhhBp; slots = slotsB; hseed = hseedB; carry = carryB;
    t0 = t0B; first = firstB;
  }
  const int kh = tid & 1;         // k-half (cols [kh*128, kh*128+128))
  const int gp = (tid >> 1) & 1;  // gate pair: 0 -> (i,g), 1 -> (f,o)
  const int u = tid >> 2;         // unit 0..255
  const int r0 = gp * 256 + u;    // i (gp=0) / f (gp=1)
  const int r1 = r0 + 512;        // g (gp=0) / o (gp=1)

  uint4 w0v[12], w1v[12];
  {
    const u32* p0 = Whhp + (size_t)r0 * 128 + kh * 64;
    const u32* p1 = Whhp + (size_t)r1 * 128 + kh * 64;
#pragma unroll
    for (int k = 0; k < 16; ++k) {
      uint4 v0 = *(const uint4*)(p0 + 4 * k);
      uint4 v1 = *(const uint4*)(p1 + 4 * k);
      if (k < 12) { w0v[k] = v0; w1v[k] = v1; }
      else { wL0[k - 12][tid] = v0; wL1[k - 12][tid] = v1; }
    }
  }
#pragma unroll
  for (int k = 0; k < 12; ++k) { pin4v(w0v[k]); pin4v(w1v[k]); }
  float c;
  if (first) {
    if (tid < 128) hbuf[0][tid] = 0u;
    c = 0.f;
  } else {
    if (tid < 128) hbuf[0][tid] = hseed[b * 128 + tid];
    c = carry[b * 256 + u];
  }
  __syncthreads();

#pragma unroll 1
  for (int tl = 0; tl < CH; ++tl) {
    const int cur = tl & 1, nxt = cur ^ 1;
    const f16* xp = xg + ((size_t)b * CH + tl) * 1024;
    const float xa = (float)xp[r0];
    const float xb = (float)xp[r1];

    float a0 = 0.f, a1 = 0.f;
#pragma unroll
    for (int k = 0; k < 16; ++k) {
      uint4 hk = *(const uint4*)&hbuf[cur][kh * 64 + 4 * k];  // 2-addr broadcast
      const uint4 wa = (k < 12) ? w0v[k] : wL0[k - 12][tid];
      const uint4 wb = (k < 12) ? w1v[k] : wL1[k - 12][tid];
      a0 = fdot2(wa.x, hk.x, a0); a0 = fdot2(wa.y, hk.y, a0);
      a0 = fdot2(wa.z, hk.z, a0); a0 = fdot2(wa.w, hk.w, a0);
      a1 = fdot2(wb.x, hk.x, a1); a1 = fdot2(wb.y, hk.y, a1);
      a1 = fdot2(wb.z, hk.z, a1); a1 = fdot2(wb.w, hk.w, a1);
    }
    // sum k-halves (kh pair = lane^1), then add input contribution
    a0 += __shfl_xor(a0, 1);
    a1 += __shfl_xor(a1, 1);
    a0 += xa; a1 += xb;
    // exchange gate partners (gp pair = lane^2)
    const float px0 = __shfl_xor(a0, 2);
    const float px1 = __shfl_xor(a1, 2);
    const float gi = sigm(gp ? px0 : a0);
    const float gf = sigm(gp ? a0 : px0);
    const float gg = tanh_(gp ? px1 : a1);
    const float go = sigm(gp ? a1 : px1);
    c = gf * c + gi * gg;               // identical in all 4 quad lanes
    const float h = go * tanh_(c);
    if ((tid & 3) == 0) {
      ((f16*)hbuf[nxt])[u] = (f16)h;
      ((f16*)(slots + ((size_t)b * NS + t0 + tl) * 128))[u] = (f16)h;
    }
    __syncthreads();  // single barrier: h(t) visible for next step
  }
  if (tid < 128) hseed[b * 128 + tid] = hbuf[0][tid];  // CH even -> final in [0]
  if ((tid & 3) == 0) carry[b * 256 + u] = c;
}

// ---------------------------------------------------------------------------
// outproj: out = Wout·h1 + b, IN PLACE over d_out slots. r11/r12 version
// (fine-grained padding col+4*(col>>5), conflict-free). Unchanged.
// ---------------------------------------------------------------------------
#define OPS 140
static __device__ __forceinline__ int swzc(int col) { return col + 4 * (col >> 5); }

__global__ __launch_bounds__(1024) void outproj_kernel(
    const float* __restrict__ Wout, const float* __restrict__ bout,
    u32* __restrict__ io) {
  const int bs = blockIdx.x;  // 2048 blocks
  const int b = bs >> 4;
  const int t0 = (bs & 15) * 64;
  const int tid = threadIdx.x;
  const int p = tid & 7;
  const int vq = tid >> 3;

  __shared__ u32 h1L[64 * OPS];
  __shared__ float outL[64 * OPS];

  const u32* src = io + ((size_t)b * NS + t0) * 128;
  uint4 s0 = *(const uint4*)(src + (size_t)tid * 8);
  uint4 s1 = *(const uint4*)(src + (size_t)tid * 8 + 4);

  u32 wo[16];
  const float* pw = Wout + (size_t)vq * NH + p * 32;
#pragma unroll
  for (int k = 0; k < 8; ++k) {
    float4 w4 = *(const float4*)(pw + 4 * k);
    wo[2 * k] = pkh(w4.x, w4.y); wo[2 * k + 1] = pkh(w4.z, w4.w);
  }
  const float bo = bout[vq];

  {
    const int sr = tid >> 4;
    const int sc = (tid & 15) * 8;
    const int base = sr * OPS + swzc(sc);
    *(uint4*)&h1L[base] = s0;
    *(uint4*)&h1L[base + 4] = s1;
  }
  __syncthreads();

#pragma unroll 4
  for (int s = 0; s < 64; ++s) {
    float oa = 0.f;
#pragma unroll
    for (int q = 0; q < 4; ++q) {
      uint4 hq = *(const uint4*)&h1L[s * OPS + swzc(p * 16 + 4 * q)];
      u32 hw[4] = {hq.x, hq.y, hq.z, hq.w};
#pragma unroll
      for (int j = 0; j < 4; ++j) oa = fdot2(wo[4 * q + j], hw[j], oa);
    }
    oa += __shfl_xor(oa, 1);
    oa += __shfl_xor(oa, 2);
    oa += __shfl_xor(oa, 4);
    if (p == 0) outL[s * OPS + swzc(vq)] = oa + bo;
  }
  __syncthreads();

  float* df = (float*)(io + ((size_t)b * NS + t0) * 128);
  {
    const int sr = tid >> 4;
    const int sc = (tid & 15) * 8;
    const int base = sr * OPS + swzc(sc);
    *(float4*)(df + (size_t)tid * 8) = *(float4*)&outL[base];
    *(float4*)(df + (size_t)tid * 8 + 4) = *(float4*)&outL[base + 4];
  }
}

extern "C" void kernel_launch(void* const* d_in, const int* in_sizes, int n_in,
                              void* d_out, int out_size, void* d_ws, size_t ws_size,
                              hipStream_t stream) {
  const float* x    = (const float*)d_in[0];
  const float* Wih0 = (const float*)d_in[1];
  const float* Whh0 = (const float*)d_in[2];
  const float* bih0 = (const float*)d_in[3];
  const float* bhh0 = (const float*)d_in[4];
  const float* Wih1 = (const float*)d_in[5];
  const float* Whh1 = (const float*)d_in[6];
  const float* bih1 = (const float*)d_in[7];
  const float* bhh1 = (const float*)d_in[8];
  const float* Wout = (const float*)d_in[9];
  const float* bout = (const float*)d_in[10];

  // ws (< 38 MiB): xg0 | xg1 | hseed/carry | packed weights
  f16* xg0 = (f16*)d_ws;
  f16* xg1 = (f16*)((char*)d_ws + (16u << 20));
  u32* hseed0 = (u32*)((char*)d_ws + (32u << 20));
  u32* hseed1 = (u32*)((char*)d_ws + (32u << 20) + (64u << 10));
  float* carry0 = (float*)((char*)d_ws + (32u << 20) + (128u << 10));
  float* carry1 = (float*)((char*)d_ws + (32u << 20) + (256u << 10));
  u32* Wih0p = (u32*)((char*)d_ws + (34u << 20));
  u32* Wih1p = (u32*)((char*)d_ws + (35u << 20));
  u32* Whh0p = (u32*)((char*)d_ws + (36u << 20));
  u32* Whh1p = (u32*)((char*)d_ws + (37u << 20));
  u32* slots = (u32*)d_out;  // h0 -> h1 -> f32 out, in place per chunk row

  prepack_kernel<<<448, 1024, 0, stream>>>(Wih0, Wih1, Whh0, Whh1,
                                           Wih0p, Wih1p, Whh0p, Whh1p);

  // prologue: gemm0(0); scan0(0)
  gemm_pair_kernel<<<512, 1024, 0, stream>>>(
      nullptr, nullptr, nullptr, nullptr, nullptr, 0, 0,
      x, Wih0p, bih0, bhh0, xg0, 0, 1);
  scan_pair_kernel<<<256, 1024, 0, stream>>>(
      nullptr, nullptr, nullptr, nullptr, nullptr, 0, 0, 0,
      xg0, Whh0p, slots, hseed0, carry0, 0, 1, 1);

  // pipeline: {gemm1(s) || gemm0(s+1)}; then {scan1(s) || scan0(s+1)}
  for (int s = 0; s < NCH; ++s) {
    const int g0on = (s + 1 < NCH);
    gemm_pair_kernel<<<512, 1024, 0, stream>>>(
        slots, Wih1p, bih1, bhh1, xg1, s * CH, 1,
        x, Wih0p, bih0, bhh0, xg0, (s + 1) * CH, g0on);
    scan_pair_kernel<<<256, 1024, 0, stream>>>(
        xg1, Whh1p, slots, hseed1, carry1, s * CH, (s == 0) ? 1 : 0, 1,
        xg0, Whh0p, slots, hseed0, carry0, (s + 1) * CH, 0, g0on);
  }
  outproj_kernel<<<2048, 1024, 0, stream>>>(Wout, bout, slots);
}

// Round 16
// 4435.708 us; speedup vs baseline: 3.1242x; 1.3476x over previous
//
#include <hip/hip_runtime.h>
#include <cstdint>

#define NB 128   // batch
#define NS 1024  // seq len
#define NV 128   // input dim
#define NH 256   // hidden
#define CH 64    // chunk length
#define NCH (NS / CH)

typedef _Float16 f16;
typedef _Float16 h2 __attribute__((ext_vector_type(2)));
typedef uint32_t u32;

static __device__ __forceinline__ float fdot2(u32 a, u32 b, float c) {
  return __builtin_amdgcn_fdot2(__builtin_bit_cast(h2, a),
                                __builtin_bit_cast(h2, b), c, false);
}
static __device__ __forceinline__ u32 pkh(float a, float b) {  // RTN
  union { h2 h; u32 u; } cv; cv.h = h2{(f16)a, (f16)b}; return cv.u;
}
static __device__ __forceinline__ u32 pkz(float a, float b) {  // RTZ (x only)
  return __builtin_bit_cast(u32, __builtin_amdgcn_cvt_pkrtz(a, b));
}
static __device__ __forceinline__ float sigm(float x) { return 1.f / (1.f + __expf(-x)); }
static __device__ __forceinline__ float tanh_(float x) { return 1.f - 2.f / (__expf(2.f * x) + 1.f); }

// Opaque asm def: allocator cannot rematerialize. ARCH VGPRs only — r13/r15
// proved AGPR homing is a dead end (dot ops can't read AGPRs; copies or worse).
static __device__ __forceinline__ void pin4v(uint4& v) {
  asm volatile("" : "+v"(v.x), "+v"(v.y), "+v"(v.z), "+v"(v.w));
}

// ---------------------------------------------------------------------------
// prepack: four weight matrices f32 -> packed f16 pairs, once per call.
// (Scans use f32+pkh directly — the r11-measured form; gemms use packed.)
// ---------------------------------------------------------------------------
__global__ __launch_bounds__(1024) void prepack_kernel(
    const float* __restrict__ Wih0, const float* __restrict__ Wih1,
    const float* __restrict__ Whh0, const float* __restrict__ Whh1,
    u32* __restrict__ Wih0p, u32* __restrict__ Wih1p,
    u32* __restrict__ Whh0p, u32* __restrict__ Whh1p) {
  const int g = blockIdx.x * 1024 + threadIdx.x;
  const float* src; u32* dst; int off;
  if (g < 65536)       { src = Wih0; dst = Wih0p; off = g; }
  else if (g < 196608) { src = Wih1; dst = Wih1p; off = g - 65536; }
  else if (g < 327680) { src = Whh0; dst = Whh0p; off = g - 196608; }
  else                 { src = Whh1; dst = Whh1p; off = g - 327680; }
  dst[off] = pkh(src[2 * off], src[2 * off + 1]);
}

// ---------------------------------------------------------------------------
// gemm pair, 512 threads (grant-128 class). r12's measured-best structure
// (prepack weights + LDS input panel with uniform-broadcast reads) with the
// pin4a handicap removed: pure pin4v 24 + 8 LDS (g1); 16 pin4v (g0).
// ---------------------------------------------------------------------------
__global__ __attribute__((amdgpu_flat_work_group_size(512, 512),
                          amdgpu_waves_per_eu(2, 2)))
void gemm_pair_kernel(
    const u32* __restrict__ g1_in, const u32* __restrict__ g1_Wp,
    const float* __restrict__ g1_bih, const float* __restrict__ g1_bhh,
    f16* __restrict__ g1_xg, int g1_t0, int g1_on,
    const float* __restrict__ g0_x, const u32* __restrict__ g0_Wp,
    const float* __restrict__ g0_bih, const float* __restrict__ g0_bhh,
    f16* __restrict__ g0_xg, int g0_t0, int g0_on) {
  __shared__ uint4 wL0[8][512];
  __shared__ uint4 wL1[8][512];
  __shared__ __align__(16) u32 panel[32 * 128];  // 16 KiB input panel
  const int blk = blockIdx.x;
  const int tid = threadIdx.x;
  const int r0 = tid, r1 = tid + 512;

  if (blk < 256) {
    if (!g1_on) return;
    const int b = blk >> 1, tpart = blk & 1;
    // stage 32 timesteps of h0 (16 KiB contiguous) -> LDS
    const uint4* src = (const uint4*)(g1_in + ((size_t)b * NS + g1_t0 + tpart * 32) * 128);
    ((uint4*)panel)[tid] = src[tid];
    ((uint4*)panel)[tid + 512] = src[tid + 512];
    uint4 w0r[24], w1r[24];
    {
      const u32* p0 = g1_Wp + (size_t)r0 * 128;
      const u32* p1 = g1_Wp + (size_t)r1 * 128;
#pragma unroll
      for (int k = 0; k < 32; ++k) {
        uint4 v0 = *(const uint4*)(p0 + 4 * k);
        uint4 v1 = *(const uint4*)(p1 + 4 * k);
        if (k < 24) { w0r[k] = v0; w1r[k] = v1; }
        else { wL0[k - 24][tid] = v0; wL1[k - 24][tid] = v1; }
      }
    }
#pragma unroll
    for (int k = 0; k < 24; ++k) { pin4v(w0r[k]); pin4v(w1r[k]); }
    const float bs0 = g1_bih[r0] + g1_bhh[r0];
    const float bs1 = g1_bih[r1] + g1_bhh[r1];
    __syncthreads();
#pragma unroll 1
    for (int tl = 0; tl < 32; ++tl) {
      float a0 = 0.f, a1 = 0.f;
#pragma unroll
      for (int k = 0; k < 32; ++k) {
        uint4 xv = *(const uint4*)&panel[tl * 128 + 4 * k];  // uniform broadcast
        uint4 wa = (k < 24) ? w0r[k] : wL0[k - 24][tid];
        uint4 wb = (k < 24) ? w1r[k] : wL1[k - 24][tid];
        a0 = fdot2(wa.x, xv.x, a0); a0 = fdot2(wa.y, xv.y, a0);
        a0 = fdot2(wa.z, xv.z, a0); a0 = fdot2(wa.w, xv.w, a0);
        a1 = fdot2(wb.x, xv.x, a1); a1 = fdot2(wb.y, xv.y, a1);
        a1 = fdot2(wb.z, xv.z, a1); a1 = fdot2(wb.w, xv.w, a1);
      }
      f16* op = g1_xg + ((size_t)b * CH + tpart * 32 + tl) * 1024;
      op[r0] = (f16)(a0 + bs0);
      op[r1] = (f16)(a1 + bs1);
    }
  } else {
    if (!g0_on) return;
    const int idx = blk - 256;
    const int b = idx >> 1, tpart = idx & 1;
    // stage 32 timesteps of x packed f32->f16 during the copy (8 KiB)
    {
      const float4* src = (const float4*)(g0_x + ((size_t)b * NS + g0_t0 + tpart * 32) * NV);
      float4 a = src[2 * tid];
      float4 c = src[2 * tid + 1];
      ((uint4*)panel)[tid] = uint4{pkz(a.x, a.y), pkz(a.z, a.w), pkz(c.x, c.y), pkz(c.z, c.w)};
    }
    uint4 w0r[16], w1r[16];
    {
      const u32* p0 = g0_Wp + (size_t)r0 * 64;
      const u32* p1 = g0_Wp + (size_t)r1 * 64;
#pragma unroll
      for (int k = 0; k < 16; ++k) {
        w0r[k] = *(const uint4*)(p0 + 4 * k);
        w1r[k] = *(const uint4*)(p1 + 4 * k);
      }
    }
#pragma unroll
    for (int k = 0; k < 16; ++k) { pin4v(w0r[k]); pin4v(w1r[k]); }
    const float bs0 = g0_bih[r0] + g0_bhh[r0];
    const float bs1 = g0_bih[r1] + g0_bhh[r1];
    __syncthreads();
#pragma unroll 1
    for (int tl = 0; tl < 32; ++tl) {
      float a0 = 0.f, a1 = 0.f;
#pragma unroll
      for (int k = 0; k < 16; ++k) {
        uint4 xv = *(const uint4*)&panel[tl * 64 + 4 * k];  // uniform broadcast
        a0 = fdot2(w0r[k].x, xv.x, a0); a0 = fdot2(w0r[k].y, xv.y, a0);
        a0 = fdot2(w0r[k].z, xv.z, a0); a0 = fdot2(w0r[k].w, xv.w, a0);
        a1 = fdot2(w1r[k].x, xv.x, a1); a1 = fdot2(w1r[k].y, xv.y, a1);
        a1 = fdot2(w1r[k].z, xv.z, a1); a1 = fdot2(w1r[k].w, xv.w, a1);
      }
      f16* op = g0_xg + ((size_t)b * CH + tpart * 32 + tl) * 1024;
      op[r0] = (f16)(a0 + bs0);
      op[r1] = (f16)(a1 + bs1);
    }
  }
}

// ---------------------------------------------------------------------------
// scan pair — BYTE-IDENTICAL to r11's measured ~92us version (512 threads,
// f32 Whh + pkh preamble, 24 pin4v + 8 tid-indexed LDS frags, h(t-1) via
// uniform ds_read_b128 broadcast, one shfl_xor partner exchange, ONE barrier
// per step). r12's regression to 171us was the pin4a split, not prepack.
// ---------------------------------------------------------------------------
__global__ __attribute__((amdgpu_flat_work_group_size(512, 512),
                          amdgpu_waves_per_eu(2, 2)))
void scan_pair_kernel(
    const f16* __restrict__ xgA, const float* __restrict__ WhhA,
    u32* __restrict__ slotsA, u32* __restrict__ hseedA, float* __restrict__ carryA,
    int t0A, int firstA, int onA,
    const f16* __restrict__ xgB, const float* __restrict__ WhhB,
    u32* __restrict__ slotsB, u32* __restrict__ hseedB, float* __restrict__ carryB,
    int t0B, int firstB, int onB) {
  __shared__ uint4 wL0[8][512];                 // r0-row overflow, tid-indexed
  __shared__ uint4 wL1[8][512];                 // r1-row overflow, tid-indexed
  __shared__ __align__(16) u32 hbuf[2][128];    // h as 256 f16, double-buffered

  const int blk = blockIdx.x;
  const int tid = threadIdx.x;
  const f16* xg; const float* Whh; u32* slots; u32* hseed; float* carry;
  int t0, first, b;
  if (blk < 128) {
    if (!onA) return;
    b = blk; xg = xgA; Whh = WhhA; slots = slotsA; hseed = hseedA; carry = carryA;
    t0 = t0A; first = firstA;
  } else {
    if (!onB) return;
    b = blk - 128; xg = xgB; Whh = WhhB; slots = slotsB; hseed = hseedB; carry = carryB;
    t0 = t0B; first = firstB;
  }
  const int p = tid & 1;
  const int u = tid >> 1;
  const int r0 = p * 256 + u;   // gate i (p=0) / f (p=1)
  const int r1 = r0 + 512;      // gate g (p=0) / o (p=1)

  uint4 w0r[24], w1r[24];
  {
    const float* p0 = Whh + (size_t)r0 * NH;
    const float* p1 = Whh + (size_t)r1 * NH;
#pragma unroll
    for (int k = 0; k < 32; ++k) {
      float4 a = *(const float4*)(p0 + 8 * k);
      float4 c2 = *(const float4*)(p0 + 8 * k + 4);
      uint4 v0 = uint4{pkh(a.x, a.y), pkh(a.z, a.w), pkh(c2.x, c2.y), pkh(c2.z, c2.w)};
      float4 d = *(const float4*)(p1 + 8 * k);
      float4 e = *(const float4*)(p1 + 8 * k + 4);
      uint4 v1 = uint4{pkh(d.x, d.y), pkh(d.z, d.w), pkh(e.x, e.y), pkh(e.z, e.w)};
      if (k < 24) { w0r[k] = v0; w1r[k] = v1; }
      else { wL0[k - 24][tid] = v0; wL1[k - 24][tid] = v1; }
    }
  }
#pragma unroll
  for (int k = 0; k < 24; ++k) { pin4v(w0r[k]); pin4v(w1r[k]); }
  float c;
  if (first) {
    if (tid < 128) hbuf[0][tid] = 0u;
    c = 0.f;
  } else {
    if (tid < 128) hbuf[0][tid] = hseed[b * 128 + tid];
    c = carry[b * 256 + u];
  }
  __syncthreads();

#pragma unroll 1
  for (int tl = 0; tl < CH; ++tl) {
    const int cur = tl & 1, nxt = cur ^ 1;
    const f16* xp = xg + ((size_t)b * CH + tl) * 1024;
    const float xa = (float)xp[r0];
    const float xb = (float)xp[r1];

    float a0 = 0.f, a1 = 0.f;
#pragma unroll
    for (int k = 0; k < 32; ++k) {
      uint4 hk = *(const uint4*)&hbuf[cur][4 * k];  // uniform addr -> broadcast
      const uint4 wa = (k < 24) ? w0r[k] : wL0[k - 24][tid];
      const uint4 wb = (k < 24) ? w1r[k] : wL1[k - 24][tid];
      a0 = fdot2(wa.x, hk.x, a0); a0 = fdot2(wa.y, hk.y, a0);
      a0 = fdot2(wa.z, hk.z, a0); a0 = fdot2(wa.w, hk.w, a0);
      a1 = fdot2(wb.x, hk.x, a1); a1 = fdot2(wb.y, hk.y, a1);
      a1 = fdot2(wb.z, hk.z, a1); a1 = fdot2(wb.w, hk.w, a1);
    }
    a0 += xa; a1 += xb;
    const float px0 = __shfl_xor(a0, 1);   // partner lane: other two gates
    const float px1 = __shfl_xor(a1, 1);
    const float ai = p ? px0 : a0;
    const float ag = p ? px1 : a1;
    const float af = p ? a0 : px0;
    const float ao = p ? a1 : px1;
    const float gi = sigm(ai), gg = tanh_(ag), gf = sigm(af), go = sigm(ao);
    c = gf * c + gi * gg;                  // redundant in both lanes (same value)
    const float h = go * tanh_(c);
    if (p == 0) {
      ((f16*)hbuf[nxt])[u] = (f16)h;
      ((f16*)(slots + ((size_t)b * NS + t0 + tl) * 128))[u] = (f16)h;
    }
    __syncthreads();  // single barrier: h(t) visible for next step
  }
  if (tid < 128) hseed[b * 128 + tid] = hbuf[0][tid];  // CH even -> final in [0]
  if (p == 0) carry[b * 256 + u] = c;
}

// ---------------------------------------------------------------------------
// outproj: out = Wout·h1 + b, IN PLACE over d_out slots. r11 version
// (fine-grained padding col+4*(col>>5), conflict-free). Unchanged.
// ---------------------------------------------------------------------------
#define OPS 140
static __device__ __forceinline__ int swzc(int col) { return col + 4 * (col >> 5); }

__global__ __launch_bounds__(1024) void outproj_kernel(
    const float* __restrict__ Wout, const float* __restrict__ bout,
    u32* __restrict__ io) {
  const int bs = blockIdx.x;  // 2048 blocks
  const int b = bs >> 4;
  const int t0 = (bs & 15) * 64;
  const int tid = threadIdx.x;
  const int p = tid & 7;
  const int vq = tid >> 3;

  __shared__ u32 h1L[64 * OPS];
  __shared__ float outL[64 * OPS];

  const u32* src = io + ((size_t)b * NS + t0) * 128;
  uint4 s0 = *(const uint4*)(src + (size_t)tid * 8);
  uint4 s1 = *(const uint4*)(src + (size_t)tid * 8 + 4);

  u32 wo[16];
  const float* pw = Wout + (size_t)vq * NH + p * 32;
#pragma unroll
  for (int k = 0; k < 8; ++k) {
    float4 w4 = *(const float4*)(pw + 4 * k);
    wo[2 * k] = pkh(w4.x, w4.y); wo[2 * k + 1] = pkh(w4.z, w4.w);
  }
  const float bo = bout[vq];

  {
    const int sr = tid >> 4;
    const int sc = (tid & 15) * 8;
    const int base = sr * OPS + swzc(sc);
    *(uint4*)&h1L[base] = s0;
    *(uint4*)&h1L[base + 4] = s1;
  }
  __syncthreads();

#pragma unroll 4
  for (int s = 0; s < 64; ++s) {
    float oa = 0.f;
#pragma unroll
    for (int q = 0; q < 4; ++q) {
      uint4 hq = *(const uint4*)&h1L[s * OPS + swzc(p * 16 + 4 * q)];
      u32 hw[4] = {hq.x, hq.y, hq.z, hq.w};
#pragma unroll
      for (int j = 0; j < 4; ++j) oa = fdot2(wo[4 * q + j], hw[j], oa);
    }
    oa += __shfl_xor(oa, 1);
    oa += __shfl_xor(oa, 2);
    oa += __shfl_xor(oa, 4);
    if (p == 0) outL[s * OPS + swzc(vq)] = oa + bo;
  }
  __syncthreads();

  float* df = (float*)(io + ((size_t)b * NS + t0) * 128);
  {
    const int sr = tid >> 4;
    const int sc = (tid & 15) * 8;
    const int base = sr * OPS + swzc(sc);
    *(float4*)(df + (size_t)tid * 8) = *(float4*)&outL[base];
    *(float4*)(df + (size_t)tid * 8 + 4) = *(float4*)&outL[base + 4];
  }
}

extern "C" void kernel_launch(void* const* d_in, const int* in_sizes, int n_in,
                              void* d_out, int out_size, void* d_ws, size_t ws_size,
                              hipStream_t stream) {
  const float* x    = (const float*)d_in[0];
  const float* Wih0 = (const float*)d_in[1];
  const float* Whh0 = (const float*)d_in[2];
  const float* bih0 = (const float*)d_in[3];
  const float* bhh0 = (const float*)d_in[4];
  const float* Wih1 = (const float*)d_in[5];
  const float* Whh1 = (const float*)d_in[6];
  const float* bih1 = (const float*)d_in[7];
  const float* bhh1 = (const float*)d_in[8];
  const float* Wout = (const float*)d_in[9];
  const float* bout = (const float*)d_in[10];

  // ws (< 38 MiB): xg0 | xg1 | hseed/carry | packed weights
  f16* xg0 = (f16*)d_ws;
  f16* xg1 = (f16*)((char*)d_ws + (16u << 20));
  u32* hseed0 = (u32*)((char*)d_ws + (32u << 20));
  u32* hseed1 = (u32*)((char*)d_ws + (32u << 20) + (64u << 10));
  float* carry0 = (float*)((char*)d_ws + (32u << 20) + (128u << 10));
  float* carry1 = (float*)((char*)d_ws + (32u << 20) + (256u << 10));
  u32* Wih0p = (u32*)((char*)d_ws + (34u << 20));
  u32* Wih1p = (u32*)((char*)d_ws + (35u << 20));
  u32* Whh0p = (u32*)((char*)d_ws + (36u << 20));
  u32* Whh1p = (u32*)((char*)d_ws + (37u << 20));
  u32* slots = (u32*)d_out;  // h0 -> h1 -> f32 out, in place per chunk row

  prepack_kernel<<<448, 1024, 0, stream>>>(Wih0, Wih1, Whh0, Whh1,
                                           Wih0p, Wih1p, Whh0p, Whh1p);

  // prologue: gemm0(0); scan0(0)
  gemm_pair_kernel<<<512, 512, 0, stream>>>(
      nullptr, nullptr, nullptr, nullptr, nullptr, 0, 0,
      x, Wih0p, bih0, bhh0, xg0, 0, 1);
  scan_pair_kernel<<<256, 512, 0, stream>>>(
      nullptr, nullptr, nullptr, nullptr, nullptr, 0, 0, 0,
      xg0, Whh0, slots, hseed0, carry0, 0, 1, 1);

  // pipeline: {gemm1(s) || gemm0(s+1)}; then {scan1(s) || scan0(s+1)}
  for (int s = 0; s < NCH; ++s) {
    const int g0on = (s + 1 < NCH);
    gemm_pair_kernel<<<512, 512, 0, stream>>>(
        slots, Wih1p, bih1, bhh1, xg1, s * CH, 1,
        x, Wih0p, bih0, bhh0, xg0, (s + 1) * CH, g0on);
    scan_pair_kernel<<<256, 512, 0, stream>>>(
        xg1, Whh1, slots, hseed1, carry1, s * CH, (s == 0) ? 1 : 0, 1,
        xg0, Whh0, slots, hseed0, carry0, (s + 1) * CH, 0, g0on);
  }
  outproj_kernel<<<2048, 1024, 0, stream>>>(Wout, bout, slots);
}